// Round 20
// baseline (732.345 us; speedup 1.0000x reference)
//
#include <hip/hip_runtime.h>
#include <hip/hip_bf16.h>
#include <cstdint>
#include <cstddef>

#define Bn 64
#define Tn 50
#define Pn 49
#define En 512
#define Hn 512
#define Vn 10000
#define IEn 1024
#define G5 2560   // 5*H

typedef __attribute__((ext_vector_type(8))) short bf16x8;
typedef __attribute__((ext_vector_type(4))) float f32x4;

__device__ __forceinline__ float sigm(float x)  { return 1.0f / (1.0f + __expf(-x)); }
__device__ __forceinline__ float tanh_f(float x){ return 1.0f - 2.0f / (1.0f + __expf(2.0f * x)); }

__device__ __forceinline__ unsigned short f2b(float f) {
    union { float f; unsigned int u; } c; c.f = f;
    unsigned int u = c.u;
    u += 0x7fffu + ((u >> 16) & 1u);   // RNE (finite values only)
    return (unsigned short)(u >> 16);
}
__device__ __forceinline__ float b2f(unsigned short u) {
    union { unsigned int u; float f; } c; c.u = ((unsigned int)u) << 16;
    return c.f;
}

// ---------------------------------------------------------------------------
// fp32 tiled GEMM (vgw only)
// ---------------------------------------------------------------------------
template<bool GATHER>
__global__ __launch_bounds__(256)
void gemm64(const float* __restrict__ A, int lda,
            const float* __restrict__ B,
            float* __restrict__ C,
            int M, int N, int K,
            const float* __restrict__ bias,
            const float* __restrict__ rowadd, int rowDiv, long rowStride,
            const int* __restrict__ gidx)
{
    const int n0 = blockIdx.x * 64;
    const int m0 = blockIdx.y * 64;
    const long koff = (long)blockIdx.z * K;
    const float* Bp = B + koff * N;
    float* Cp = C + (gridDim.z > 1 ? (size_t)blockIdx.z * (size_t)M * (size_t)N : (size_t)0);

    __shared__ float As[16][64];
    __shared__ float Bs[16][64];

    const int tid = threadIdx.x;
    const int tx = tid & 15;
    const int ty = tid >> 4;
    const int ra = tid >> 2;
    const int ca = (tid & 3) << 2;

    long arow = GATHER ? (long)gidx[m0 + ra] : (long)(m0 + ra);
    const float* Arow = A + arow * (long)lda + koff + ca;

    const int kl = ty;
    const int nb = tx << 2;
    const int ncol = n0 + nb;

    float acc[4][4] = {{0.f,0.f,0.f,0.f},{0.f,0.f,0.f,0.f},{0.f,0.f,0.f,0.f},{0.f,0.f,0.f,0.f}};

    for (int k0 = 0; k0 < K; k0 += 16) {
        float4 av = *(const float4*)(Arow + k0);
        float4 bv;
        const float* bptr = Bp + (long)(k0 + kl) * N + ncol;
        if (ncol + 3 < N) {
            bv = *(const float4*)bptr;
        } else {
            bv.x = (ncol + 0 < N) ? bptr[0] : 0.f;
            bv.y = (ncol + 1 < N) ? bptr[1] : 0.f;
            bv.z = (ncol + 2 < N) ? bptr[2] : 0.f;
            bv.w = (ncol + 3 < N) ? bptr[3] : 0.f;
        }
        __syncthreads();
        As[ca + 0][ra] = av.x; As[ca + 1][ra] = av.y;
        As[ca + 2][ra] = av.z; As[ca + 3][ra] = av.w;
        *(float4*)&Bs[kl][nb] = bv;
        __syncthreads();
        #pragma unroll
        for (int kk = 0; kk < 16; kk++) {
            const float4 a = *(const float4*)&As[kk][ty << 2];
            const float4 b = *(const float4*)&Bs[kk][tx << 2];
            const float a_[4] = {a.x, a.y, a.z, a.w};
            const float b_[4] = {b.x, b.y, b.z, b.w};
            #pragma unroll
            for (int i = 0; i < 4; i++)
                #pragma unroll
                for (int j = 0; j < 4; j++)
                    acc[i][j] = fmaf(a_[i], b_[j], acc[i][j]);
        }
    }

    #pragma unroll
    for (int i = 0; i < 4; i++) {
        const int rr = m0 + (ty << 2) + i;
        #pragma unroll
        for (int j = 0; j < 4; j++) {
            const int cc = n0 + (tx << 2) + j;
            if (cc < N) {
                float v = acc[i][j];
                if (bias)   v += bias[cc];
                if (rowadd) v += rowadd[(long)(rr / rowDiv) * rowStride + cc];
                Cp[(long)rr * N + cc] = v;
            }
        }
    }
}

// ---------------------------------------------------------------------------
// bf16 MFMA GEMM (R8/R10-proven): C = A @ BT^T, fp32 accum. 128x128 tile, BK=32.
// 4 waves (2x2). GM: gather/scatter via ridx. SWZ: XCD-chunk swizzle.
// ---------------------------------------------------------------------------
template<int OUTF, int OUTB, int GM, int SWZ>
__global__ __launch_bounds__(256)
void gemm_mfma(const unsigned short* __restrict__ A,
               const unsigned short* __restrict__ BT,
               float* __restrict__ Cf, unsigned short* __restrict__ Cb,
               int M, int N, int K,
               const float* __restrict__ bias,
               const float* __restrict__ rowadd, int rowDiv,
               const int* __restrict__ ridx, const int* __restrict__ dcnt,
               int mtiles)
{
    __shared__ __align__(16) unsigned short Asm[128][40];
    __shared__ __align__(16) unsigned short Bsm[128][40];

    int Meff = M;
    if (GM) Meff = *dcnt;
    int m0, n0;
    if (SWZ) {
        const int nwg = gridDim.x;
        const int q = nwg >> 3, rm = nwg & 7;
        const int xcd = blockIdx.x & 7, pos = blockIdx.x >> 3;
        const int swz = (xcd < rm ? xcd * (q + 1) : rm * (q + 1) + (xcd - rm) * q) + pos;
        m0 = (swz % mtiles) * 128;
        n0 = (swz / mtiles) * 128;
    } else {
        n0 = blockIdx.x * 128;
        m0 = blockIdx.y * 128;
    }
    if (GM && m0 >= Meff) return;

    const int tid = threadIdx.x;
    const int lane = tid & 63;
    const int wid = tid >> 6;
    const int wm = wid >> 1;
    const int wn = wid & 1;

    const int r0 = tid >> 2;
    const int kg = tid & 3;

    const int ar0 = m0 + r0, ar1 = m0 + r0 + 64;
    const int br0 = n0 + r0, br1 = n0 + r0 + 64;
    long arow0, arow1;
    if (GM) {
        arow0 = (ar0 < Meff) ? (long)ridx[ar0] : 0;
        arow1 = (ar1 < Meff) ? (long)ridx[ar1] : 0;
    } else {
        arow0 = ar0; arow1 = ar1;
    }

    f32x4 acc[4][4] = {};
    const uint4 zero4 = {0u, 0u, 0u, 0u};

    uint4 a0, a1, b0, b1;
    {
        const long ka = (long)kg * 8;
        a0 = (GM || ar0 < Meff) ? *(const uint4*)(A + arow0 * K + ka) : zero4;
        a1 = (GM || ar1 < Meff) ? *(const uint4*)(A + arow1 * K + ka) : zero4;
        b0 = (br0 < N) ? *(const uint4*)(BT + (long)br0 * K + ka) : zero4;
        b1 = (br1 < N) ? *(const uint4*)(BT + (long)br1 * K + ka) : zero4;
    }

    for (int k0 = 0; k0 < K; k0 += 32) {
        __syncthreads();
        *(uint4*)&Asm[r0     ][kg * 8] = a0;
        *(uint4*)&Asm[r0 + 64][kg * 8] = a1;
        *(uint4*)&Bsm[r0     ][kg * 8] = b0;
        *(uint4*)&Bsm[r0 + 64][kg * 8] = b1;
        __syncthreads();

        if (k0 + 32 < K) {
            const long ka = (long)(k0 + 32) + kg * 8;
            a0 = (GM || ar0 < Meff) ? *(const uint4*)(A + arow0 * K + ka) : zero4;
            a1 = (GM || ar1 < Meff) ? *(const uint4*)(A + arow1 * K + ka) : zero4;
            b0 = (br0 < N) ? *(const uint4*)(BT + (long)br0 * K + ka) : zero4;
            b1 = (br1 < N) ? *(const uint4*)(BT + (long)br1 * K + ka) : zero4;
        }

        bf16x8 af[4], bfr[4];
        const int arow = wm * 64 + (lane & 15);
        const int brow = wn * 64 + (lane & 15);
        const int kcol = (lane >> 4) * 8;
        #pragma unroll
        for (int i = 0; i < 4; i++) {
            af[i]  = *(const bf16x8*)&Asm[arow + i * 16][kcol];
            bfr[i] = *(const bf16x8*)&Bsm[brow + i * 16][kcol];
        }
        #pragma unroll
        for (int mi = 0; mi < 4; mi++)
            #pragma unroll
            for (int ni = 0; ni < 4; ni++)
                acc[mi][ni] = __builtin_amdgcn_mfma_f32_16x16x32_bf16(af[mi], bfr[ni], acc[mi][ni], 0, 0, 0);
    }

    const int crow = m0 + wm * 64 + (lane >> 4) * 4;
    const int ccol0 = n0 + wn * 64 + (lane & 15);
    #pragma unroll
    for (int ni = 0; ni < 4; ni++) {
        const int col = ccol0 + ni * 16;
        if (col >= N) continue;
        const float bvv = bias ? bias[col] : 0.f;
        #pragma unroll
        for (int mi = 0; mi < 4; mi++) {
            #pragma unroll
            for (int r = 0; r < 4; r++) {
                const int rr = crow + mi * 16 + r;
                if (rr < Meff) {
                    const long orow = GM ? (long)ridx[rr] : (long)rr;
                    float v = acc[mi][ni][r] + bvv;
                    if (rowadd) v += rowadd[(orow / rowDiv) * N + col];
                    if (OUTF) Cf[orow * N + col] = v;
                    if (OUTB) Cb[orow * N + col] = f2b(v);
                }
            }
        }
    }
}

// ---------------------------------------------------------------------------
// Dual GEMM: PH (z=0) and PS (z=1) in one launch (R17-proven).
// ---------------------------------------------------------------------------
__global__ __launch_bounds__(256)
void gemm_dual(const unsigned short* __restrict__ A0, const unsigned short* __restrict__ BT0,
               float* __restrict__ C0, const float* __restrict__ bias0,
               const unsigned short* __restrict__ A1, const unsigned short* __restrict__ BT1,
               float* __restrict__ C1, const float* __restrict__ bias1,
               int N, int K,
               const int* __restrict__ ridx, const int* __restrict__ dcnt)
{
    __shared__ __align__(16) unsigned short Asm[128][40];
    __shared__ __align__(16) unsigned short Bsm[128][40];

    const unsigned short* A  = blockIdx.z ? A1 : A0;
    const unsigned short* BT = blockIdx.z ? BT1 : BT0;
    float* Cf                = blockIdx.z ? C1 : C0;
    const float* bias        = blockIdx.z ? bias1 : bias0;

    const int Meff = *dcnt;
    const int n0 = blockIdx.x * 128;
    const int m0 = blockIdx.y * 128;
    if (m0 >= Meff) return;

    const int tid = threadIdx.x;
    const int lane = tid & 63;
    const int wid = tid >> 6;
    const int wm = wid >> 1;
    const int wn = wid & 1;

    const int r0 = tid >> 2;
    const int kg = tid & 3;

    const int ar0 = m0 + r0, ar1 = m0 + r0 + 64;
    const int br0 = n0 + r0, br1 = n0 + r0 + 64;
    const long arow0 = (ar0 < Meff) ? (long)ridx[ar0] : 0;
    const long arow1 = (ar1 < Meff) ? (long)ridx[ar1] : 0;

    f32x4 acc[4][4] = {};
    const uint4 zero4 = {0u, 0u, 0u, 0u};

    uint4 a0, a1, b0, b1;
    {
        const long ka = (long)kg * 8;
        a0 = *(const uint4*)(A + arow0 * K + ka);
        a1 = *(const uint4*)(A + arow1 * K + ka);
        b0 = (br0 < N) ? *(const uint4*)(BT + (long)br0 * K + ka) : zero4;
        b1 = (br1 < N) ? *(const uint4*)(BT + (long)br1 * K + ka) : zero4;
    }

    for (int k0 = 0; k0 < K; k0 += 32) {
        __syncthreads();
        *(uint4*)&Asm[r0     ][kg * 8] = a0;
        *(uint4*)&Asm[r0 + 64][kg * 8] = a1;
        *(uint4*)&Bsm[r0     ][kg * 8] = b0;
        *(uint4*)&Bsm[r0 + 64][kg * 8] = b1;
        __syncthreads();

        if (k0 + 32 < K) {
            const long ka = (long)(k0 + 32) + kg * 8;
            a0 = *(const uint4*)(A + arow0 * K + ka);
            a1 = *(const uint4*)(A + arow1 * K + ka);
            b0 = (br0 < N) ? *(const uint4*)(BT + (long)br0 * K + ka) : zero4;
            b1 = (br1 < N) ? *(const uint4*)(BT + (long)br1 * K + ka) : zero4;
        }

        bf16x8 af[4], bfr[4];
        const int arow = wm * 64 + (lane & 15);
        const int brow = wn * 64 + (lane & 15);
        const int kcol = (lane >> 4) * 8;
        #pragma unroll
        for (int i = 0; i < 4; i++) {
            af[i]  = *(const bf16x8*)&Asm[arow + i * 16][kcol];
            bfr[i] = *(const bf16x8*)&Bsm[brow + i * 16][kcol];
        }
        #pragma unroll
        for (int mi = 0; mi < 4; mi++)
            #pragma unroll
            for (int ni = 0; ni < 4; ni++)
                acc[mi][ni] = __builtin_amdgcn_mfma_f32_16x16x32_bf16(af[mi], bfr[ni], acc[mi][ni], 0, 0, 0);
    }

    const int crow = m0 + wm * 64 + (lane >> 4) * 4;
    const int ccol0 = n0 + wn * 64 + (lane & 15);
    #pragma unroll
    for (int ni = 0; ni < 4; ni++) {
        const int col = ccol0 + ni * 16;
        if (col >= N) continue;
        const float bvv = bias[col];
        #pragma unroll
        for (int mi = 0; mi < 4; mi++) {
            #pragma unroll
            for (int r = 0; r < 4; r++) {
                const int rr = crow + mi * 16 + r;
                if (rr < Meff) {
                    const long orow = (long)ridx[rr];
                    Cf[orow * N + col] = acc[mi][ni][r] + bvv;
                }
            }
        }
    }
}

// ---------------------------------------------------------------------------
// Logits GEMM: 128x256 tile, BK=32, 8 waves (2x4, wave tile 64x64). R18.
// ---------------------------------------------------------------------------
__global__ __launch_bounds__(512)
void gemm_8w(const unsigned short* __restrict__ A,
             const unsigned short* __restrict__ BT,
             float* __restrict__ Cf,
             int N, int K,
             const float* __restrict__ bias,
             const int* __restrict__ ridx, const int* __restrict__ dcnt,
             int mtiles)
{
    __shared__ __align__(16) unsigned short Asm[128][40];
    __shared__ __align__(16) unsigned short Bsm[256][40];

    const int Meff = *dcnt;
    int m0, n0;
    {
        const int nwg = gridDim.x;
        const int q = nwg >> 3, rm = nwg & 7;
        const int xcd = blockIdx.x & 7, pos = blockIdx.x >> 3;
        const int swz = (xcd < rm ? xcd * (q + 1) : rm * (q + 1) + (xcd - rm) * q) + pos;
        m0 = (swz % mtiles) * 128;
        n0 = (swz / mtiles) * 256;
    }
    if (m0 >= Meff) return;

    const int tid = threadIdx.x;
    const int lane = tid & 63;
    const int wid = tid >> 6;        // 0..7
    const int wm = wid >> 2;         // 0..1 (64-row half)
    const int wn = wid & 3;          // 0..3 (64-col quarter)

    const int r0 = tid >> 2;         // 0..127 staging row
    const int kg = tid & 3;          // 16B k-seg

    const int ar = m0 + r0;
    const int br0 = n0 + r0, br1 = n0 + r0 + 128;
    const long arow = (ar < Meff) ? (long)ridx[ar] : 0;
    const bool bv0 = (br0 < N), bv1 = (br1 < N);

    f32x4 acc[4][4] = {};
    const uint4 zero4 = {0u, 0u, 0u, 0u};

    uint4 aR, bR0, bR1;
    {
        const long ka = (long)kg * 8;
        aR  = *(const uint4*)(A + arow * K + ka);
        bR0 = bv0 ? *(const uint4*)(BT + (long)br0 * K + ka) : zero4;
        bR1 = bv1 ? *(const uint4*)(BT + (long)br1 * K + ka) : zero4;
    }

    const int arowf = wm * 64 + (lane & 15);
    const int browf = wn * 64 + (lane & 15);
    const int kcol = (lane >> 4) * 8;

    for (int k0 = 0; k0 < K; k0 += 32) {
        __syncthreads();
        *(uint4*)&Asm[r0][kg * 8] = aR;
        *(uint4*)&Bsm[r0      ][kg * 8] = bR0;
        *(uint4*)&Bsm[r0 + 128][kg * 8] = bR1;
        __syncthreads();

        if (k0 + 32 < K) {
            const long ka = (long)(k0 + 32) + kg * 8;
            aR  = *(const uint4*)(A + arow * K + ka);
            bR0 = bv0 ? *(const uint4*)(BT + (long)br0 * K + ka) : zero4;
            bR1 = bv1 ? *(const uint4*)(BT + (long)br1 * K + ka) : zero4;
        }

        bf16x8 af[4], bfr[4];
        #pragma unroll
        for (int i = 0; i < 4; i++) {
            af[i]  = *(const bf16x8*)&Asm[arowf + i * 16][kcol];
            bfr[i] = *(const bf16x8*)&Bsm[browf + i * 16][kcol];
        }
        #pragma unroll
        for (int mi = 0; mi < 4; mi++)
            #pragma unroll
            for (int ni = 0; ni < 4; ni++)
                acc[mi][ni] = __builtin_amdgcn_mfma_f32_16x16x32_bf16(af[mi], bfr[ni], acc[mi][ni], 0, 0, 0);
    }

    const int crow = m0 + wm * 64 + (lane >> 4) * 4;
    const int ccol0 = n0 + wn * 64 + (lane & 15);
    #pragma unroll
    for (int ni = 0; ni < 4; ni++) {
        const int col = ccol0 + ni * 16;
        if (col >= N) continue;
        const float bvv = bias[col];
        #pragma unroll
        for (int mi = 0; mi < 4; mi++) {
            #pragma unroll
            for (int r = 0; r < 4; r++) {
                const int rr = crow + mi * 16 + r;
                if (rr < Meff) {
                    const long orow = (long)ridx[rr];
                    Cf[orow * N + col] = acc[mi][ni][r] + bvv;
                }
            }
        }
    }
}

// ---------------------------------------------------------------------------
// ALL weight transposes in ONE launch (R17-proven segment map).
// ---------------------------------------------------------------------------
__global__ __launch_bounds__(256)
void mega_transpose(const float* __restrict__ Wv, unsigned short* __restrict__ WvT,
                    const float* __restrict__ Wl, unsigned short* __restrict__ WlT0,
                    unsigned short* __restrict__ W3T,
                    const float* __restrict__ Wav, const float* __restrict__ Wah,
                    const float* __restrict__ Was,
                    unsigned short* __restrict__ WavT, unsigned short* __restrict__ WahT,
                    unsigned short* __restrict__ WasT,
                    const float* __restrict__ Wp, unsigned short* __restrict__ WpT)
{
    int t = blockIdx.x;
    const float* in; unsigned short* out; int K, N, istride, bx, by;
    if (t < 512)            { in = Wv;  out = WvT;  K = 1024; N = 512;  istride = 512;  bx = t & 15;  by = t >> 4; }
    else if ((t -= 512) < 1280)  { in = Wl;  out = WlT0; K = 512;  N = G5;   istride = G5;   bx = t % 80;  by = t / 80; }
    else if ((t -= 1280) < 1280) { in = Wl + (size_t)1024 * G5; out = W3T; K = 512; N = G5; istride = G5; bx = t % 80; by = t / 80; }
    else if ((t -= 1280) < 256)  { in = Wav; out = WavT; K = 512; N = 512; istride = 512; bx = t & 15; by = t >> 4; }
    else if ((t -= 256) < 256)   { in = Wah; out = WahT; K = 512; N = 512; istride = 512; bx = t & 15; by = t >> 4; }
    else if ((t -= 256) < 256)   { in = Was; out = WasT; K = 512; N = 512; istride = 512; bx = t & 15; by = t >> 4; }
    else                         { t -= 256; in = Wp; out = WpT; K = 512; N = Vn; istride = Vn; bx = t % 313; by = t / 313; }

    __shared__ float tile[32][33];
    const int k0 = by * 32;
    const int n0 = bx * 32;
    const int tx = threadIdx.x & 31, ty = threadIdx.x >> 5;
    #pragma unroll
    for (int j = 0; j < 4; j++) {
        int k = k0 + ty + j * 8, n = n0 + tx;
        tile[ty + j * 8][tx] = (k < K && n < N) ? in[(long)k * istride + n] : 0.f;
    }
    __syncthreads();
    #pragma unroll
    for (int j = 0; j < 4; j++) {
        int n = n0 + ty + j * 8, k = k0 + tx;
        if (n < N && k < K) out[(long)n * K + k] = f2b(tile[tx][ty + j * 8]);
    }
}

// ---------------------------------------------------------------------------
// Prep conversions in ONE launch (R17-proven segment map).
// ---------------------------------------------------------------------------
__global__ __launch_bounds__(256)
void prep_convert(const float* __restrict__ v, unsigned short* __restrict__ vB,
                  const float* __restrict__ emb, const int* __restrict__ w,
                  unsigned short* __restrict__ WEb,
                  const int* __restrict__ len, int* __restrict__ ridx,
                  int* __restrict__ dcnt)
{
    const int blk = blockIdx.x, tid = threadIdx.x;
    if (blk < 3136) {
        const int i = blk * 256 + tid;
        float4 x = ((const float4*)v)[i];
        ushort4 u;
        u.x = f2b(x.x); u.y = f2b(x.y); u.z = f2b(x.z); u.w = f2b(x.w);
        ((ushort4*)vB)[i] = u;
    } else if (blk < 4736) {
        const int r = (blk - 3136) * 2 + (tid >> 7);
        const int c = tid & 127;
        const long row = w[r];
        float4 x = ((const float4*)(emb + row * 512))[c];
        ushort4 u;
        u.x = f2b(x.x); u.y = f2b(x.y); u.z = f2b(x.z); u.w = f2b(x.w);
        ((ushort4*)(WEb + (long)r * 512))[c] = u;
    } else {
        if (tid < 64) {
            const int b = tid;
            int L = len[b]; L = L < 0 ? 0 : (L > Tn ? Tn : L);
            int off = L;
            #pragma unroll
            for (int s = 1; s < 64; s <<= 1) {
                int n = __shfl_up(off, s);
                if (b >= s) off += n;
            }
            const int start = off - L;
            if (b == 63) *dcnt = off;
            for (int t = 0; t < L; t++) ridx[start + t] = b * Tn + t;
        }
    }
}

// FUSED: vg = mean_p vproj[b,p,:]; h0 = vg@Wh+bh (bf16); m0 = vg@Wm+bm. (R18)
__global__ void vg_h0m0(const unsigned short* __restrict__ vproj,
                        const float* __restrict__ Wh, const float* __restrict__ bh,
                        const float* __restrict__ Wm, const float* __restrict__ bm,
                        float* __restrict__ vg,
                        unsigned short* __restrict__ h0b, float* __restrict__ m)
{
    __shared__ float vgs[512];
    const int b = blockIdx.x, e = threadIdx.x;
    const unsigned short* p = vproj + (long)b * Pn * En + e;
    float s = 0.f;
    #pragma unroll 7
    for (int q = 0; q < Pn; q++) s += b2f(p[q * En]);
    s *= (1.0f / 49.0f);
    vgs[e] = s;
    vg[b * 512 + e] = s;
    __syncthreads();
    float a1 = bh[e], a2 = bm[e];
    #pragma unroll 8
    for (int k = 0; k < 512; k++) {
        const float x = vgs[k];
        a1 = fmaf(x, Wh[(long)k * 512 + e], a1);
        a2 = fmaf(x, Wm[(long)k * 512 + e], a2);
    }
    h0b[b * 512 + e] = f2b(a1);
    m[b * 512 + e] = a2;
}

// ---------------------------------------------------------------------------
// Fused LSTM step, ONE LAUNCH PER t (R15/16/17-proven).
// ---------------------------------------------------------------------------
__global__ __launch_bounds__(256)
void scan_step(int t, const float* __restrict__ base,
               const unsigned short* __restrict__ hcur,
               unsigned short* __restrict__ hnxt,
               float* __restrict__ mF,
               const unsigned short* __restrict__ W3T,  // [2560][512]
               unsigned short* __restrict__ Hsb,
               unsigned short* __restrict__ Ssb)
{
    __shared__ __align__(16) unsigned short Wh_s[5][8][520];

    const int tid = threadIdx.x;
    const int lane = tid & 63, wv = tid >> 6;
    const int e0 = blockIdx.x * 8;
    const int col = lane & 15;
    const int fk = (lane >> 4) * 8;
    const int bb = wv * 16 + (lane & 15);     // A-frag batch row

    bf16x8 Ah[16];
    #pragma unroll
    for (int ch = 0; ch < 16; ch++)
        Ah[ch] = *(const bf16x8*)(hcur + (long)bb * 512 + ch * 32 + fk);

    for (int idx = tid; idx < 40 * 64; idx += 256) {
        const int row = idx >> 6, seg = idx & 63;
        const int g = row >> 3, c = row & 7;
        *(uint4*)&Wh_s[g][c][seg * 8] =
            *(const uint4*)(W3T + (long)(g * 512 + e0 + c) * 512 + seg * 8);
    }

    const int rbase = wv * 16 + (lane >> 4) * 4;
    const int ecol = e0 + (col & 7);
    float bse[5][4], mv[4];
    if (col < 8) {
        #pragma unroll
        for (int r = 0; r < 4; r++) {
            const long rrow = (long)(rbase + r) * Tn + t;
            const float* bp = base + rrow * G5 + ecol;
            bse[0][r] = bp[0];    bse[1][r] = bp[512];  bse[2][r] = bp[1024];
            bse[3][r] = bp[1536]; bse[4][r] = bp[2048];
            mv[r] = mF[(rbase + r) * 512 + ecol];
        }
    }

    __syncthreads();

    const unsigned short* B0 = &Wh_s[(col >> 3)    ][col & 7][0];
    const unsigned short* B1 = &Wh_s[2 + (col >> 3)][col & 7][0];
    const unsigned short* B2 = &Wh_s[4][col & 7][0];

    f32x4 a0 = {}, a1 = {}, a2 = {};
    #pragma unroll
    for (int ch = 0; ch < 16; ch++) {
        const int ko = ch * 32 + fk;
        a0 = __builtin_amdgcn_mfma_f32_16x16x32_bf16(Ah[ch], *(const bf16x8*)(B0 + ko), a0, 0, 0, 0);
        a1 = __builtin_amdgcn_mfma_f32_16x16x32_bf16(Ah[ch], *(const bf16x8*)(B1 + ko), a1, 0, 0, 0);
        a2 = __builtin_amdgcn_mfma_f32_16x16x32_bf16(Ah[ch], *(const bf16x8*)(B2 + ko), a2, 0, 0, 0);
    }

    #pragma unroll
    for (int r = 0; r < 4; r++) {
        const float fsh = __shfl_xor(a0[r], 8);
        const float gsh = __shfl_xor(a1[r], 8);
        if (col < 8) {
            const int b = rbase + r;
            const float gi = a0[r] + bse[0][r];
            const float gf = fsh   + bse[1][r];
            const float go = a1[r] + bse[2][r];
            const float gg = gsh   + bse[3][r];
            const float g5 = a2[r] + bse[4][r];
            const float iv = sigm(gi), fv = sigm(gf), ov = sigm(go);
            const float mn = fmaf(iv, tanh_f(g5), fv * mv[r]);
            const float tm = tanh_f(mn);
            const float hh = ov * tm, ss = gg * tm;
            const unsigned short hhi = f2b(hh);
            const long hoff = (long)b * 512 + ecol;
            const long rrow = (long)b * Tn + t;
            mF[hoff] = mn;
            hnxt[hoff] = hhi;
            Hsb[rrow * 512 + ecol] = hhi;
            Ssb[rrow * 512 + ecol] = f2b(ss);
        }
    }
}

// Per-(b,t) adaptive attention; h from bf16 Hsb; early-exit masked rows.
__global__ __launch_bounds__(256)
void attn(const unsigned short* __restrict__ vproj, const float* __restrict__ pv,
          const float* __restrict__ PH, const float* __restrict__ PS,
          const unsigned short* __restrict__ Hsb, const float* __restrict__ Waz,
          const float* __restrict__ baz, unsigned short* __restrict__ CHb,
          const int* __restrict__ len)
{
    const int r = (blockIdx.x & 7) * 400 + (blockIdx.x >> 3);   // bijective, 3200=8*400
    const int b = r / Tn;
    if ((r % Tn) >= len[b]) return;
    const int tid = threadIdx.x;
    const int lane = tid & 63, wid = tid >> 6;

    __shared__ float ps_s[512];
    __shared__ float ph_s[512];
    __shared__ float alog[64];

    for (int i = tid; i < 512; i += 256) {
        ps_s[i] = PS[(long)r * 512 + i];
        ph_s[i] = PH[(long)r * 512 + i];
    }
    __syncthreads();

    const float4 wz0 = *(const float4*)(Waz + lane * 8);
    const float4 wz1 = *(const float4*)(Waz + lane * 8 + 4);
    const float4 q0  = *(const float4*)&ps_s[lane * 8];
    const float4 q1  = *(const float4*)&ps_s[lane * 8 + 4];

    for (int slot = wid; slot < Pn + 1; slot += 4) {
        const float* src = (slot < Pn) ? (pv + ((long)b * Pn + slot) * 512)
                                       : (const float*)ph_s;
        const float4 x0 = *(const float4*)(src + lane * 8);
        const float4 x1 = *(const float4*)(src + lane * 8 + 4);
        float d = 0.f;
        d = fmaf(tanh_f(x0.x + q0.x), wz0.x, d);
        d = fmaf(tanh_f(x0.y + q0.y), wz0.y, d);
        d = fmaf(tanh_f(x0.z + q0.z), wz0.z, d);
        d = fmaf(tanh_f(x0.w + q0.w), wz0.w, d);
        d = fmaf(tanh_f(x1.x + q1.x), wz1.x, d);
        d = fmaf(tanh_f(x1.y + q1.y), wz1.y, d);
        d = fmaf(tanh_f(x1.z + q1.z), wz1.z, d);
        d = fmaf(tanh_f(x1.w + q1.w), wz1.w, d);
        #pragma unroll
        for (int s = 32; s >= 1; s >>= 1) d += __shfl_xor(d, s);
        if (lane == 0) alog[slot] = d + baz[0];
    }
    __syncthreads();

    if (wid == 0) {
        const float v = (lane < Pn + 1) ? alog[lane] : -3.4e38f;
        float mx = v;
        #pragma unroll
        for (int s = 32; s >= 1; s >>= 1) mx = fmaxf(mx, __shfl_xor(mx, s));
        const float ev = (lane < Pn + 1) ? __expf(v - mx) : 0.f;
        float sm = ev;
        #pragma unroll
        for (int s = 32; s >= 1; s >>= 1) sm += __shfl_xor(sm, s);
        if (lane < Pn + 1) alog[lane] = ev / sm;
    }
    __syncthreads();

    const float a49 = alog[Pn];
    for (int ee = tid; ee < 512; ee += 256) {
        const float hval = b2f(Hsb[(long)r * 512 + ee]);
        float c = a49 * hval;
        const unsigned short* vp = vproj + (long)b * Pn * 512 + ee;
        #pragma unroll 7
        for (int q = 0; q < Pn; q++) c = fmaf(alog[q], b2f(vp[q * 512]), c);
        CHb[(long)r * 512 + ee] = f2b(c + hval);
    }
}

// register-resident row softmax (single global read) + length mask
__global__ __launch_bounds__(256)
void softmax_mask(float* __restrict__ out, const int* __restrict__ lengths)
{
    const int r = blockIdx.x, b = r / Tn, t = r % Tn;
    float* row = out + (long)r * Vn;
    const int tid = threadIdx.x;
    float4* row4 = (float4*)row;

    if (t >= lengths[b]) {
        f32x4* rowv = (f32x4*)row;
        const f32x4 z = {0.f, 0.f, 0.f, 0.f};
        for (int i = tid; i < Vn / 4; i += 256)
            __builtin_nontemporal_store(z, &rowv[i]);
        return;
    }

    __shared__ float red[4];
    const int lane = tid & 63, wid = tid >> 6;

    float4 rv[10];
    float mx = -3.4e38f;
    #pragma unroll
    for (int j = 0; j < 10; j++) {
        const int i = tid + j * 256;
        if (i < Vn / 4) {
            rv[j] = row4[i];
            mx = fmaxf(mx, fmaxf(fmaxf(rv[j].x, rv[j].y), fmaxf(rv[j].z, rv[j].w)));
        }
    }
    #pragma unroll
    for (int s = 32; s >= 1; s >>= 1) mx = fmaxf(mx, __shfl_xor(mx, s));
    if (lane == 0) red[wid] = mx;
    __syncthreads();
    mx = fmaxf(fmaxf(red[0], red[1]), fmaxf(red[2], red[3]));
    __syncthreads();

    float sm = 0.f;
    #pragma unroll
    for (int j = 0; j < 10; j++) {
        const int i = tid + j * 256;
        if (i < Vn / 4) {
            rv[j].x = __expf(rv[j].x - mx);
            rv[j].y = __expf(rv[j].y - mx);
            rv[j].z = __expf(rv[j].z - mx);
            rv[j].w = __expf(rv[j].w - mx);
            sm += rv[j].x + rv[j].y + rv[j].z + rv[j].w;
        }
    }
    #pragma unroll
    for (int s = 32; s >= 1; s >>= 1) sm += __shfl_xor(sm, s);
    if (lane == 0) red[wid] = sm;
    __syncthreads();
    sm = red[0] + red[1] + red[2] + red[3];
    const float inv = 1.0f / sm;

    #pragma unroll
    for (int j = 0; j < 10; j++) {
        const int i = tid + j * 256;
        if (i < Vn / 4) {
            rv[j].x *= inv; rv[j].y *= inv; rv[j].z *= inv; rv[j].w *= inv;
            row4[i] = rv[j];
        }
    }
}

extern "C" void kernel_launch(void* const* d_in, const int* in_sizes, int n_in,
                              void* d_out, int out_size, void* d_ws, size_t ws_size,
                              hipStream_t stream)
{
    (void)in_sizes; (void)n_in; (void)out_size; (void)ws_size;
    const float* v   = (const float*)d_in[0];
    const int*   w   = (const int*)  d_in[1];
    const int*   len = (const int*)  d_in[2];
    const float* emb = (const float*)d_in[3];
    const float* Wv  = (const float*)d_in[4];
    const float* bv  = (const float*)d_in[5];
    const float* Wh  = (const float*)d_in[6];
    const float* bh  = (const float*)d_in[7];
    const float* Wm  = (const float*)d_in[8];
    const float* bm  = (const float*)d_in[9];
    const float* Wl  = (const float*)d_in[10];
    const float* bl  = (const float*)d_in[11];
    const float* Wav = (const float*)d_in[12];
    const float* bav = (const float*)d_in[13];
    const float* Wah = (const float*)d_in[14];
    const float* bah = (const float*)d_in[15];
    const float* Was = (const float*)d_in[16];
    const float* bas = (const float*)d_in[17];
    const float* Waz = (const float*)d_in[18];
    const float* baz = (const float*)d_in[19];
    const float* Wp  = (const float*)d_in[20];
    const float* bp  = (const float*)d_in[21];
    float* out_f = (float*)d_out;

    // ---- workspace carve ----
    char* wsp = (char*)d_ws;
    size_t off = 0;
    auto walloc = [&](size_t bytes) -> void* {
        void* r = wsp + off;
        off += (bytes + 255) & ~(size_t)255;
        return r;
    };
    unsigned short* WpT    = (unsigned short*)walloc((size_t)Vn * 512 * 2);
    unsigned short* WvT    = (unsigned short*)walloc((size_t)512 * 1024 * 2);
    unsigned short* WlT0   = (unsigned short*)walloc((size_t)G5 * 512 * 2);
    unsigned short* WavT   = (unsigned short*)walloc((size_t)512 * 512 * 2);
    unsigned short* WahT   = (unsigned short*)walloc((size_t)512 * 512 * 2);
    unsigned short* WasT   = (unsigned short*)walloc((size_t)512 * 512 * 2);
    unsigned short* vprojb = (unsigned short*)walloc((size_t)3136 * 512 * 2);
    unsigned short* CHb    = (unsigned short*)walloc((size_t)3200 * 512 * 2);
    float* vg   = (float*)walloc((size_t)64 * 512 * 4);
    unsigned short* hB = (unsigned short*)walloc((size_t)2 * 64 * 512 * 2);  // ping-pong h (bf16)
    float* mbuf = (float*)walloc((size_t)64 * 512 * 4);
    float* vgw  = (float*)walloc((size_t)64 * G5 * 4);
    int*   ridx = (int*)walloc((size_t)3200 * 4);
    int*   dcnt = (int*)walloc(256);

    // ---- scratch in dead upper region of d_out (dead before logits GEMM) ----
    char* sp = (char*)(out_f + (size_t)3200 * G5);
    size_t off2 = 0;
    auto salloc = [&](size_t bytes) -> void* {
        void* r = sp + off2;
        off2 += (bytes + 255) & ~(size_t)255;
        return r;
    };
    unsigned short* vB  = (unsigned short*)salloc((size_t)3136 * 1024 * 2);
    unsigned short* WEb = (unsigned short*)salloc((size_t)3200 * 512 * 2);
    float* pvb = (float*)salloc((size_t)3136 * 512 * 4);
    unsigned short* Hsb = (unsigned short*)salloc((size_t)3200 * 512 * 2);
    unsigned short* Ssb = (unsigned short*)salloc((size_t)3200 * 512 * 2);
    float* PHb = (float*)salloc((size_t)3200 * 512 * 4);
    float* PSb = (float*)salloc((size_t)3200 * 512 * 4);
    unsigned short* W3T = (unsigned short*)salloc((size_t)G5 * 512 * 2);

    // ---- prep: ONE transpose launch + ONE convert/gather/compact launch ----
    mega_transpose<<<8848, 256, 0, stream>>>(Wv, WvT, Wl, WlT0, W3T,
                                             Wav, Wah, Was, WavT, WahT, WasT,
                                             Wp, WpT);
    prep_convert<<<4737, 256, 0, stream>>>(v, vB, emb, w, WEb, len, ridx, dcnt);

    // 1. vproj(bf16) = v @ Wv + bv
    gemm_mfma<0,1,0,0><<<dim3(4, 25), 256, 0, stream>>>(vB, WvT, nullptr, vprojb,
                                                        3136, 512, 1024, bv, nullptr, 1,
                                                        nullptr, nullptr, 0);
    // 2-3. fused vg + h0 (bf16 -> ping-pong slot 0) + m0
    vg_h0m0<<<64, 512, 0, stream>>>(vprojb, Wh, bh, Wm, bm, vg, hB, mbuf);
    // 4. vgw = vg @ Wl[512:1024] + bl (fp32)
    gemm64<false><<<dim3(40, 1, 1), 256, 0, stream>>>(vg, 512, Wl + (size_t)512 * G5, vgw,
                                                      64, G5, 512, bl, nullptr, 1, 0, nullptr);
    // 5. pv = vproj @ Wav + bav
    gemm_mfma<1,0,0,0><<<dim3(4, 25), 256, 0, stream>>>(vprojb, WavT, pvb, nullptr,
                                                        3136, 512, 512, bav, nullptr, 1,
                                                        nullptr, nullptr, 0);
    // 6. base = we @ Wl[0:512] + vgw[b] -> d_out rows (ACTIVE rows only:
    //    dead rows' h-chain tail never reaches a checked output)
    gemm_mfma<1,0,1,1><<<500, 256, 0, stream>>>(WEb, WlT0, out_f, nullptr,
                                                3200, G5, 512, nullptr, vgw, Tn,
                                                ridx, dcnt, 25);
    // 7. 50-step scan: one fused launch per step (stream order = barrier)
    for (int t = 0; t < Tn; t++) {
        const size_t cur = (size_t)(t & 1) * (64 * 512);
        const size_t nxt = (size_t)((t + 1) & 1) * (64 * 512);
        scan_step<<<64, 256, 0, stream>>>(t, out_f, hB + cur, hB + nxt, mbuf, W3T,
                                          Hsb, Ssb);
    }
    // 8. PH + PS in one z=2 launch (active rows only)
    gemm_dual<<<dim3(4, 25, 2), 256, 0, stream>>>(Hsb, WahT, PHb, bah,
                                                  Ssb, WasT, PSb, bas,
                                                  512, 512, ridx, dcnt);
    // 9. attention -> CH (bf16), active rows only (XCD-local b)
    attn<<<3200, 256, 0, stream>>>(vprojb, pvb, PHb, PSb, Hsb, Waz, baz, CHb, len);
    // 10. logits = CH @ Wp + bp -> d_out (128x256 tile, 8 waves, 64x64/wave)
    gemm_8w<<<520, 512, 0, stream>>>(CHb, WpT, out_f, Vn, 512, bp, ridx, dcnt, 13);
    // 11. softmax + mask
    softmax_mask<<<3200, 256, 0, stream>>>(out_f, len);
}

// Round 21
// 716.136 us; speedup vs baseline: 1.0226x; 1.0226x over previous
//
#include <hip/hip_runtime.h>
#include <hip/hip_bf16.h>
#include <cstdint>
#include <cstddef>

#define Bn 64
#define Tn 50
#define Pn 49
#define En 512
#define Hn 512
#define Vn 10000
#define IEn 1024
#define G5 2560   // 5*H

typedef __attribute__((ext_vector_type(8))) short bf16x8;
typedef __attribute__((ext_vector_type(4))) float f32x4;

__device__ __forceinline__ float sigm(float x)  { return 1.0f / (1.0f + __expf(-x)); }
__device__ __forceinline__ float tanh_f(float x){ return 1.0f - 2.0f / (1.0f + __expf(2.0f * x)); }

__device__ __forceinline__ unsigned short f2b(float f) {
    union { float f; unsigned int u; } c; c.f = f;
    unsigned int u = c.u;
    u += 0x7fffu + ((u >> 16) & 1u);   // RNE (finite values only)
    return (unsigned short)(u >> 16);
}
__device__ __forceinline__ float b2f(unsigned short u) {
    union { unsigned int u; float f; } c; c.u = ((unsigned int)u) << 16;
    return c.f;
}

// ---------------------------------------------------------------------------
// fp32 tiled GEMM (vgw only)
// ---------------------------------------------------------------------------
template<bool GATHER>
__global__ __launch_bounds__(256)
void gemm64(const float* __restrict__ A, int lda,
            const float* __restrict__ B,
            float* __restrict__ C,
            int M, int N, int K,
            const float* __restrict__ bias,
            const float* __restrict__ rowadd, int rowDiv, long rowStride,
            const int* __restrict__ gidx)
{
    const int n0 = blockIdx.x * 64;
    const int m0 = blockIdx.y * 64;
    const long koff = (long)blockIdx.z * K;
    const float* Bp = B + koff * N;
    float* Cp = C + (gridDim.z > 1 ? (size_t)blockIdx.z * (size_t)M * (size_t)N : (size_t)0);

    __shared__ float As[16][64];
    __shared__ float Bs[16][64];

    const int tid = threadIdx.x;
    const int tx = tid & 15;
    const int ty = tid >> 4;
    const int ra = tid >> 2;
    const int ca = (tid & 3) << 2;

    long arow = GATHER ? (long)gidx[m0 + ra] : (long)(m0 + ra);
    const float* Arow = A + arow * (long)lda + koff + ca;

    const int kl = ty;
    const int nb = tx << 2;
    const int ncol = n0 + nb;

    float acc[4][4] = {{0.f,0.f,0.f,0.f},{0.f,0.f,0.f,0.f},{0.f,0.f,0.f,0.f},{0.f,0.f,0.f,0.f}};

    for (int k0 = 0; k0 < K; k0 += 16) {
        float4 av = *(const float4*)(Arow + k0);
        float4 bv;
        const float* bptr = Bp + (long)(k0 + kl) * N + ncol;
        if (ncol + 3 < N) {
            bv = *(const float4*)bptr;
        } else {
            bv.x = (ncol + 0 < N) ? bptr[0] : 0.f;
            bv.y = (ncol + 1 < N) ? bptr[1] : 0.f;
            bv.z = (ncol + 2 < N) ? bptr[2] : 0.f;
            bv.w = (ncol + 3 < N) ? bptr[3] : 0.f;
        }
        __syncthreads();
        As[ca + 0][ra] = av.x; As[ca + 1][ra] = av.y;
        As[ca + 2][ra] = av.z; As[ca + 3][ra] = av.w;
        *(float4*)&Bs[kl][nb] = bv;
        __syncthreads();
        #pragma unroll
        for (int kk = 0; kk < 16; kk++) {
            const float4 a = *(const float4*)&As[kk][ty << 2];
            const float4 b = *(const float4*)&Bs[kk][tx << 2];
            const float a_[4] = {a.x, a.y, a.z, a.w};
            const float b_[4] = {b.x, b.y, b.z, b.w};
            #pragma unroll
            for (int i = 0; i < 4; i++)
                #pragma unroll
                for (int j = 0; j < 4; j++)
                    acc[i][j] = fmaf(a_[i], b_[j], acc[i][j]);
        }
    }

    #pragma unroll
    for (int i = 0; i < 4; i++) {
        const int rr = m0 + (ty << 2) + i;
        #pragma unroll
        for (int j = 0; j < 4; j++) {
            const int cc = n0 + (tx << 2) + j;
            if (cc < N) {
                float v = acc[i][j];
                if (bias)   v += bias[cc];
                if (rowadd) v += rowadd[(long)(rr / rowDiv) * rowStride + cc];
                Cp[(long)rr * N + cc] = v;
            }
        }
    }
}

// ---------------------------------------------------------------------------
// bf16 MFMA GEMM (R8/R10-proven): C = A @ BT^T, fp32 accum. 128x128 tile, BK=32.
// 4 waves (2x2). GM: gather/scatter via ridx. SWZ: XCD-chunk swizzle.
// ---------------------------------------------------------------------------
template<int OUTF, int OUTB, int GM, int SWZ>
__global__ __launch_bounds__(256)
void gemm_mfma(const unsigned short* __restrict__ A,
               const unsigned short* __restrict__ BT,
               float* __restrict__ Cf, unsigned short* __restrict__ Cb,
               int M, int N, int K,
               const float* __restrict__ bias,
               const float* __restrict__ rowadd, int rowDiv,
               const int* __restrict__ ridx, const int* __restrict__ dcnt,
               int mtiles)
{
    __shared__ __align__(16) unsigned short Asm[128][40];
    __shared__ __align__(16) unsigned short Bsm[128][40];

    int Meff = M;
    if (GM) Meff = *dcnt;
    int m0, n0;
    if (SWZ) {
        const int nwg = gridDim.x;
        const int q = nwg >> 3, rm = nwg & 7;
        const int xcd = blockIdx.x & 7, pos = blockIdx.x >> 3;
        const int swz = (xcd < rm ? xcd * (q + 1) : rm * (q + 1) + (xcd - rm) * q) + pos;
        m0 = (swz % mtiles) * 128;
        n0 = (swz / mtiles) * 128;
    } else {
        n0 = blockIdx.x * 128;
        m0 = blockIdx.y * 128;
    }
    if (GM && m0 >= Meff) return;

    const int tid = threadIdx.x;
    const int lane = tid & 63;
    const int wid = tid >> 6;
    const int wm = wid >> 1;
    const int wn = wid & 1;

    const int r0 = tid >> 2;
    const int kg = tid & 3;

    const int ar0 = m0 + r0, ar1 = m0 + r0 + 64;
    const int br0 = n0 + r0, br1 = n0 + r0 + 64;
    long arow0, arow1;
    if (GM) {
        arow0 = (ar0 < Meff) ? (long)ridx[ar0] : 0;
        arow1 = (ar1 < Meff) ? (long)ridx[ar1] : 0;
    } else {
        arow0 = ar0; arow1 = ar1;
    }

    f32x4 acc[4][4] = {};
    const uint4 zero4 = {0u, 0u, 0u, 0u};

    uint4 a0, a1, b0, b1;
    {
        const long ka = (long)kg * 8;
        a0 = (GM || ar0 < Meff) ? *(const uint4*)(A + arow0 * K + ka) : zero4;
        a1 = (GM || ar1 < Meff) ? *(const uint4*)(A + arow1 * K + ka) : zero4;
        b0 = (br0 < N) ? *(const uint4*)(BT + (long)br0 * K + ka) : zero4;
        b1 = (br1 < N) ? *(const uint4*)(BT + (long)br1 * K + ka) : zero4;
    }

    for (int k0 = 0; k0 < K; k0 += 32) {
        __syncthreads();
        *(uint4*)&Asm[r0     ][kg * 8] = a0;
        *(uint4*)&Asm[r0 + 64][kg * 8] = a1;
        *(uint4*)&Bsm[r0     ][kg * 8] = b0;
        *(uint4*)&Bsm[r0 + 64][kg * 8] = b1;
        __syncthreads();

        if (k0 + 32 < K) {
            const long ka = (long)(k0 + 32) + kg * 8;
            a0 = (GM || ar0 < Meff) ? *(const uint4*)(A + arow0 * K + ka) : zero4;
            a1 = (GM || ar1 < Meff) ? *(const uint4*)(A + arow1 * K + ka) : zero4;
            b0 = (br0 < N) ? *(const uint4*)(BT + (long)br0 * K + ka) : zero4;
            b1 = (br1 < N) ? *(const uint4*)(BT + (long)br1 * K + ka) : zero4;
        }

        bf16x8 af[4], bfr[4];
        const int arow = wm * 64 + (lane & 15);
        const int brow = wn * 64 + (lane & 15);
        const int kcol = (lane >> 4) * 8;
        #pragma unroll
        for (int i = 0; i < 4; i++) {
            af[i]  = *(const bf16x8*)&Asm[arow + i * 16][kcol];
            bfr[i] = *(const bf16x8*)&Bsm[brow + i * 16][kcol];
        }
        #pragma unroll
        for (int mi = 0; mi < 4; mi++)
            #pragma unroll
            for (int ni = 0; ni < 4; ni++)
                acc[mi][ni] = __builtin_amdgcn_mfma_f32_16x16x32_bf16(af[mi], bfr[ni], acc[mi][ni], 0, 0, 0);
    }

    const int crow = m0 + wm * 64 + (lane >> 4) * 4;
    const int ccol0 = n0 + wn * 64 + (lane & 15);
    #pragma unroll
    for (int ni = 0; ni < 4; ni++) {
        const int col = ccol0 + ni * 16;
        if (col >= N) continue;
        const float bvv = bias ? bias[col] : 0.f;
        #pragma unroll
        for (int mi = 0; mi < 4; mi++) {
            #pragma unroll
            for (int r = 0; r < 4; r++) {
                const int rr = crow + mi * 16 + r;
                if (rr < Meff) {
                    const long orow = GM ? (long)ridx[rr] : (long)rr;
                    float v = acc[mi][ni][r] + bvv;
                    if (rowadd) v += rowadd[(orow / rowDiv) * N + col];
                    if (OUTF) Cf[orow * N + col] = v;
                    if (OUTB) Cb[orow * N + col] = f2b(v);
                }
            }
        }
    }
}

// ---------------------------------------------------------------------------
// Dual GEMM: PH (z=0) and PS (z=1) in one launch (R17-proven).
// ---------------------------------------------------------------------------
__global__ __launch_bounds__(256)
void gemm_dual(const unsigned short* __restrict__ A0, const unsigned short* __restrict__ BT0,
               float* __restrict__ C0, const float* __restrict__ bias0,
               const unsigned short* __restrict__ A1, const unsigned short* __restrict__ BT1,
               float* __restrict__ C1, const float* __restrict__ bias1,
               int N, int K,
               const int* __restrict__ ridx, const int* __restrict__ dcnt)
{
    __shared__ __align__(16) unsigned short Asm[128][40];
    __shared__ __align__(16) unsigned short Bsm[128][40];

    const unsigned short* A  = blockIdx.z ? A1 : A0;
    const unsigned short* BT = blockIdx.z ? BT1 : BT0;
    float* Cf                = blockIdx.z ? C1 : C0;
    const float* bias        = blockIdx.z ? bias1 : bias0;

    const int Meff = *dcnt;
    const int n0 = blockIdx.x * 128;
    const int m0 = blockIdx.y * 128;
    if (m0 >= Meff) return;

    const int tid = threadIdx.x;
    const int lane = tid & 63;
    const int wid = tid >> 6;
    const int wm = wid >> 1;
    const int wn = wid & 1;

    const int r0 = tid >> 2;
    const int kg = tid & 3;

    const int ar0 = m0 + r0, ar1 = m0 + r0 + 64;
    const int br0 = n0 + r0, br1 = n0 + r0 + 64;
    const long arow0 = (ar0 < Meff) ? (long)ridx[ar0] : 0;
    const long arow1 = (ar1 < Meff) ? (long)ridx[ar1] : 0;

    f32x4 acc[4][4] = {};
    const uint4 zero4 = {0u, 0u, 0u, 0u};

    uint4 a0, a1, b0, b1;
    {
        const long ka = (long)kg * 8;
        a0 = *(const uint4*)(A + arow0 * K + ka);
        a1 = *(const uint4*)(A + arow1 * K + ka);
        b0 = (br0 < N) ? *(const uint4*)(BT + (long)br0 * K + ka) : zero4;
        b1 = (br1 < N) ? *(const uint4*)(BT + (long)br1 * K + ka) : zero4;
    }

    for (int k0 = 0; k0 < K; k0 += 32) {
        __syncthreads();
        *(uint4*)&Asm[r0     ][kg * 8] = a0;
        *(uint4*)&Asm[r0 + 64][kg * 8] = a1;
        *(uint4*)&Bsm[r0     ][kg * 8] = b0;
        *(uint4*)&Bsm[r0 + 64][kg * 8] = b1;
        __syncthreads();

        if (k0 + 32 < K) {
            const long ka = (long)(k0 + 32) + kg * 8;
            a0 = *(const uint4*)(A + arow0 * K + ka);
            a1 = *(const uint4*)(A + arow1 * K + ka);
            b0 = (br0 < N) ? *(const uint4*)(BT + (long)br0 * K + ka) : zero4;
            b1 = (br1 < N) ? *(const uint4*)(BT + (long)br1 * K + ka) : zero4;
        }

        bf16x8 af[4], bfr[4];
        const int arow = wm * 64 + (lane & 15);
        const int brow = wn * 64 + (lane & 15);
        const int kcol = (lane >> 4) * 8;
        #pragma unroll
        for (int i = 0; i < 4; i++) {
            af[i]  = *(const bf16x8*)&Asm[arow + i * 16][kcol];
            bfr[i] = *(const bf16x8*)&Bsm[brow + i * 16][kcol];
        }
        #pragma unroll
        for (int mi = 0; mi < 4; mi++)
            #pragma unroll
            for (int ni = 0; ni < 4; ni++)
                acc[mi][ni] = __builtin_amdgcn_mfma_f32_16x16x32_bf16(af[mi], bfr[ni], acc[mi][ni], 0, 0, 0);
    }

    const int crow = m0 + wm * 64 + (lane >> 4) * 4;
    const int ccol0 = n0 + wn * 64 + (lane & 15);
    #pragma unroll
    for (int ni = 0; ni < 4; ni++) {
        const int col = ccol0 + ni * 16;
        if (col >= N) continue;
        const float bvv = bias[col];
        #pragma unroll
        for (int mi = 0; mi < 4; mi++) {
            #pragma unroll
            for (int r = 0; r < 4; r++) {
                const int rr = crow + mi * 16 + r;
                if (rr < Meff) {
                    const long orow = (long)ridx[rr];
                    Cf[orow * N + col] = acc[mi][ni][r] + bvv;
                }
            }
        }
    }
}

// ---------------------------------------------------------------------------
// Logits GEMM: 128x256 tile, BK=32, 8 waves (2x4, wave tile 64x64). R18.
// ---------------------------------------------------------------------------
__global__ __launch_bounds__(512)
void gemm_8w(const unsigned short* __restrict__ A,
             const unsigned short* __restrict__ BT,
             float* __restrict__ Cf,
             int N, int K,
             const float* __restrict__ bias,
             const int* __restrict__ ridx, const int* __restrict__ dcnt,
             int mtiles)
{
    __shared__ __align__(16) unsigned short Asm[128][40];
    __shared__ __align__(16) unsigned short Bsm[256][40];

    const int Meff = *dcnt;
    int m0, n0;
    {
        const int nwg = gridDim.x;
        const int q = nwg >> 3, rm = nwg & 7;
        const int xcd = blockIdx.x & 7, pos = blockIdx.x >> 3;
        const int swz = (xcd < rm ? xcd * (q + 1) : rm * (q + 1) + (xcd - rm) * q) + pos;
        m0 = (swz % mtiles) * 128;
        n0 = (swz / mtiles) * 256;
    }
    if (m0 >= Meff) return;

    const int tid = threadIdx.x;
    const int lane = tid & 63;
    const int wid = tid >> 6;        // 0..7
    const int wm = wid >> 2;         // 0..1 (64-row half)
    const int wn = wid & 3;          // 0..3 (64-col quarter)

    const int r0 = tid >> 2;         // 0..127 staging row
    const int kg = tid & 3;          // 16B k-seg

    const int ar = m0 + r0;
    const int br0 = n0 + r0, br1 = n0 + r0 + 128;
    const long arow = (ar < Meff) ? (long)ridx[ar] : 0;
    const bool bv0 = (br0 < N), bv1 = (br1 < N);

    f32x4 acc[4][4] = {};
    const uint4 zero4 = {0u, 0u, 0u, 0u};

    uint4 aR, bR0, bR1;
    {
        const long ka = (long)kg * 8;
        aR  = *(const uint4*)(A + arow * K + ka);
        bR0 = bv0 ? *(const uint4*)(BT + (long)br0 * K + ka) : zero4;
        bR1 = bv1 ? *(const uint4*)(BT + (long)br1 * K + ka) : zero4;
    }

    const int arowf = wm * 64 + (lane & 15);
    const int browf = wn * 64 + (lane & 15);
    const int kcol = (lane >> 4) * 8;

    for (int k0 = 0; k0 < K; k0 += 32) {
        __syncthreads();
        *(uint4*)&Asm[r0][kg * 8] = aR;
        *(uint4*)&Bsm[r0      ][kg * 8] = bR0;
        *(uint4*)&Bsm[r0 + 128][kg * 8] = bR1;
        __syncthreads();

        if (k0 + 32 < K) {
            const long ka = (long)(k0 + 32) + kg * 8;
            aR  = *(const uint4*)(A + arow * K + ka);
            bR0 = bv0 ? *(const uint4*)(BT + (long)br0 * K + ka) : zero4;
            bR1 = bv1 ? *(const uint4*)(BT + (long)br1 * K + ka) : zero4;
        }

        bf16x8 af[4], bfr[4];
        #pragma unroll
        for (int i = 0; i < 4; i++) {
            af[i]  = *(const bf16x8*)&Asm[arowf + i * 16][kcol];
            bfr[i] = *(const bf16x8*)&Bsm[browf + i * 16][kcol];
        }
        #pragma unroll
        for (int mi = 0; mi < 4; mi++)
            #pragma unroll
            for (int ni = 0; ni < 4; ni++)
                acc[mi][ni] = __builtin_amdgcn_mfma_f32_16x16x32_bf16(af[mi], bfr[ni], acc[mi][ni], 0, 0, 0);
    }

    const int crow = m0 + wm * 64 + (lane >> 4) * 4;
    const int ccol0 = n0 + wn * 64 + (lane & 15);
    #pragma unroll
    for (int ni = 0; ni < 4; ni++) {
        const int col = ccol0 + ni * 16;
        if (col >= N) continue;
        const float bvv = bias[col];
        #pragma unroll
        for (int mi = 0; mi < 4; mi++) {
            #pragma unroll
            for (int r = 0; r < 4; r++) {
                const int rr = crow + mi * 16 + r;
                if (rr < Meff) {
                    const long orow = (long)ridx[rr];
                    Cf[orow * N + col] = acc[mi][ni][r] + bvv;
                }
            }
        }
    }
}

// ---------------------------------------------------------------------------
// ALL weight transposes in ONE launch (R17-proven segment map).
// ---------------------------------------------------------------------------
__global__ __launch_bounds__(256)
void mega_transpose(const float* __restrict__ Wv, unsigned short* __restrict__ WvT,
                    const float* __restrict__ Wl, unsigned short* __restrict__ WlT0,
                    unsigned short* __restrict__ W3T,
                    const float* __restrict__ Wav, const float* __restrict__ Wah,
                    const float* __restrict__ Was,
                    unsigned short* __restrict__ WavT, unsigned short* __restrict__ WahT,
                    unsigned short* __restrict__ WasT,
                    const float* __restrict__ Wp, unsigned short* __restrict__ WpT)
{
    int t = blockIdx.x;
    const float* in; unsigned short* out; int K, N, istride, bx, by;
    if (t < 512)            { in = Wv;  out = WvT;  K = 1024; N = 512;  istride = 512;  bx = t & 15;  by = t >> 4; }
    else if ((t -= 512) < 1280)  { in = Wl;  out = WlT0; K = 512;  N = G5;   istride = G5;   bx = t % 80;  by = t / 80; }
    else if ((t -= 1280) < 1280) { in = Wl + (size_t)1024 * G5; out = W3T; K = 512; N = G5; istride = G5; bx = t % 80; by = t / 80; }
    else if ((t -= 1280) < 256)  { in = Wav; out = WavT; K = 512; N = 512; istride = 512; bx = t & 15; by = t >> 4; }
    else if ((t -= 256) < 256)   { in = Wah; out = WahT; K = 512; N = 512; istride = 512; bx = t & 15; by = t >> 4; }
    else if ((t -= 256) < 256)   { in = Was; out = WasT; K = 512; N = 512; istride = 512; bx = t & 15; by = t >> 4; }
    else                         { t -= 256; in = Wp; out = WpT; K = 512; N = Vn; istride = Vn; bx = t % 313; by = t / 313; }

    __shared__ float tile[32][33];
    const int k0 = by * 32;
    const int n0 = bx * 32;
    const int tx = threadIdx.x & 31, ty = threadIdx.x >> 5;
    #pragma unroll
    for (int j = 0; j < 4; j++) {
        int k = k0 + ty + j * 8, n = n0 + tx;
        tile[ty + j * 8][tx] = (k < K && n < N) ? in[(long)k * istride + n] : 0.f;
    }
    __syncthreads();
    #pragma unroll
    for (int j = 0; j < 4; j++) {
        int n = n0 + ty + j * 8, k = k0 + tx;
        if (n < N && k < K) out[(long)n * K + k] = f2b(tile[tx][ty + j * 8]);
    }
}

// ---------------------------------------------------------------------------
// Prep conversions in ONE launch (R17-proven segment map).
// ---------------------------------------------------------------------------
__global__ __launch_bounds__(256)
void prep_convert(const float* __restrict__ v, unsigned short* __restrict__ vB,
                  const float* __restrict__ emb, const int* __restrict__ w,
                  unsigned short* __restrict__ WEb,
                  const int* __restrict__ len, int* __restrict__ ridx,
                  int* __restrict__ dcnt)
{
    const int blk = blockIdx.x, tid = threadIdx.x;
    if (blk < 3136) {
        const int i = blk * 256 + tid;
        float4 x = ((const float4*)v)[i];
        ushort4 u;
        u.x = f2b(x.x); u.y = f2b(x.y); u.z = f2b(x.z); u.w = f2b(x.w);
        ((ushort4*)vB)[i] = u;
    } else if (blk < 4736) {
        const int r = (blk - 3136) * 2 + (tid >> 7);
        const int c = tid & 127;
        const long row = w[r];
        float4 x = ((const float4*)(emb + row * 512))[c];
        ushort4 u;
        u.x = f2b(x.x); u.y = f2b(x.y); u.z = f2b(x.z); u.w = f2b(x.w);
        ((ushort4*)(WEb + (long)r * 512))[c] = u;
    } else {
        if (tid < 64) {
            const int b = tid;
            int L = len[b]; L = L < 0 ? 0 : (L > Tn ? Tn : L);
            int off = L;
            #pragma unroll
            for (int s = 1; s < 64; s <<= 1) {
                int n = __shfl_up(off, s);
                if (b >= s) off += n;
            }
            const int start = off - L;
            if (b == 63) *dcnt = off;
            for (int t = 0; t < L; t++) ridx[start + t] = b * Tn + t;
        }
    }
}

// FUSED: vg = mean_p vproj[b,p,:]; h0 = vg@Wh+bh (bf16); m0 = vg@Wm+bm. (R18)
__global__ void vg_h0m0(const unsigned short* __restrict__ vproj,
                        const float* __restrict__ Wh, const float* __restrict__ bh,
                        const float* __restrict__ Wm, const float* __restrict__ bm,
                        float* __restrict__ vg,
                        unsigned short* __restrict__ h0b, float* __restrict__ m)
{
    __shared__ float vgs[512];
    const int b = blockIdx.x, e = threadIdx.x;
    const unsigned short* p = vproj + (long)b * Pn * En + e;
    float s = 0.f;
    #pragma unroll 7
    for (int q = 0; q < Pn; q++) s += b2f(p[q * En]);
    s *= (1.0f / 49.0f);
    vgs[e] = s;
    vg[b * 512 + e] = s;
    __syncthreads();
    float a1 = bh[e], a2 = bm[e];
    #pragma unroll 8
    for (int k = 0; k < 512; k++) {
        const float x = vgs[k];
        a1 = fmaf(x, Wh[(long)k * 512 + e], a1);
        a2 = fmaf(x, Wm[(long)k * 512 + e], a2);
    }
    h0b[b * 512 + e] = f2b(a1);
    m[b * 512 + e] = a2;
}

// ---------------------------------------------------------------------------
// Fused LSTM step, ONE LAUNCH PER t (R15/16/17-proven).
// ---------------------------------------------------------------------------
__global__ __launch_bounds__(256)
void scan_step(int t, const float* __restrict__ base,
               const unsigned short* __restrict__ hcur,
               unsigned short* __restrict__ hnxt,
               float* __restrict__ mF,
               const unsigned short* __restrict__ W3T,  // [2560][512]
               unsigned short* __restrict__ Hsb,
               unsigned short* __restrict__ Ssb)
{
    __shared__ __align__(16) unsigned short Wh_s[5][8][520];

    const int tid = threadIdx.x;
    const int lane = tid & 63, wv = tid >> 6;
    const int e0 = blockIdx.x * 8;
    const int col = lane & 15;
    const int fk = (lane >> 4) * 8;
    const int bb = wv * 16 + (lane & 15);     // A-frag batch row

    bf16x8 Ah[16];
    #pragma unroll
    for (int ch = 0; ch < 16; ch++)
        Ah[ch] = *(const bf16x8*)(hcur + (long)bb * 512 + ch * 32 + fk);

    for (int idx = tid; idx < 40 * 64; idx += 256) {
        const int row = idx >> 6, seg = idx & 63;
        const int g = row >> 3, c = row & 7;
        *(uint4*)&Wh_s[g][c][seg * 8] =
            *(const uint4*)(W3T + (long)(g * 512 + e0 + c) * 512 + seg * 8);
    }

    const int rbase = wv * 16 + (lane >> 4) * 4;
    const int ecol = e0 + (col & 7);
    float bse[5][4], mv[4];
    if (col < 8) {
        #pragma unroll
        for (int r = 0; r < 4; r++) {
            const long rrow = (long)(rbase + r) * Tn + t;
            const float* bp = base + rrow * G5 + ecol;
            bse[0][r] = bp[0];    bse[1][r] = bp[512];  bse[2][r] = bp[1024];
            bse[3][r] = bp[1536]; bse[4][r] = bp[2048];
            mv[r] = mF[(rbase + r) * 512 + ecol];
        }
    }

    __syncthreads();

    const unsigned short* B0 = &Wh_s[(col >> 3)    ][col & 7][0];
    const unsigned short* B1 = &Wh_s[2 + (col >> 3)][col & 7][0];
    const unsigned short* B2 = &Wh_s[4][col & 7][0];

    f32x4 a0 = {}, a1 = {}, a2 = {};
    #pragma unroll
    for (int ch = 0; ch < 16; ch++) {
        const int ko = ch * 32 + fk;
        a0 = __builtin_amdgcn_mfma_f32_16x16x32_bf16(Ah[ch], *(const bf16x8*)(B0 + ko), a0, 0, 0, 0);
        a1 = __builtin_amdgcn_mfma_f32_16x16x32_bf16(Ah[ch], *(const bf16x8*)(B1 + ko), a1, 0, 0, 0);
        a2 = __builtin_amdgcn_mfma_f32_16x16x32_bf16(Ah[ch], *(const bf16x8*)(B2 + ko), a2, 0, 0, 0);
    }

    #pragma unroll
    for (int r = 0; r < 4; r++) {
        const float fsh = __shfl_xor(a0[r], 8);
        const float gsh = __shfl_xor(a1[r], 8);
        if (col < 8) {
            const int b = rbase + r;
            const float gi = a0[r] + bse[0][r];
            const float gf = fsh   + bse[1][r];
            const float go = a1[r] + bse[2][r];
            const float gg = gsh   + bse[3][r];
            const float g5 = a2[r] + bse[4][r];
            const float iv = sigm(gi), fv = sigm(gf), ov = sigm(go);
            const float mn = fmaf(iv, tanh_f(g5), fv * mv[r]);
            const float tm = tanh_f(mn);
            const float hh = ov * tm, ss = gg * tm;
            const unsigned short hhi = f2b(hh);
            const long hoff = (long)b * 512 + ecol;
            const long rrow = (long)b * Tn + t;
            mF[hoff] = mn;
            hnxt[hoff] = hhi;
            Hsb[rrow * 512 + ecol] = hhi;
            Ssb[rrow * 512 + ecol] = f2b(ss);
        }
    }
}

// Per-(b,t) adaptive attention; h from bf16 Hsb; early-exit masked rows.
__global__ __launch_bounds__(256)
void attn(const unsigned short* __restrict__ vproj, const float* __restrict__ pv,
          const float* __restrict__ PH, const float* __restrict__ PS,
          const unsigned short* __restrict__ Hsb, const float* __restrict__ Waz,
          const float* __restrict__ baz, unsigned short* __restrict__ CHb,
          const int* __restrict__ len)
{
    const int r = (blockIdx.x & 7) * 400 + (blockIdx.x >> 3);   // bijective, 3200=8*400
    const int b = r / Tn;
    if ((r % Tn) >= len[b]) return;
    const int tid = threadIdx.x;
    const int lane = tid & 63, wid = tid >> 6;

    __shared__ float ps_s[512];
    __shared__ float ph_s[512];
    __shared__ float alog[64];

    for (int i = tid; i < 512; i += 256) {
        ps_s[i] = PS[(long)r * 512 + i];
        ph_s[i] = PH[(long)r * 512 + i];
    }
    __syncthreads();

    const float4 wz0 = *(const float4*)(Waz + lane * 8);
    const float4 wz1 = *(const float4*)(Waz + lane * 8 + 4);
    const float4 q0  = *(const float4*)&ps_s[lane * 8];
    const float4 q1  = *(const float4*)&ps_s[lane * 8 + 4];

    for (int slot = wid; slot < Pn + 1; slot += 4) {
        const float* src = (slot < Pn) ? (pv + ((long)b * Pn + slot) * 512)
                                       : (const float*)ph_s;
        const float4 x0 = *(const float4*)(src + lane * 8);
        const float4 x1 = *(const float4*)(src + lane * 8 + 4);
        float d = 0.f;
        d = fmaf(tanh_f(x0.x + q0.x), wz0.x, d);
        d = fmaf(tanh_f(x0.y + q0.y), wz0.y, d);
        d = fmaf(tanh_f(x0.z + q0.z), wz0.z, d);
        d = fmaf(tanh_f(x0.w + q0.w), wz0.w, d);
        d = fmaf(tanh_f(x1.x + q1.x), wz1.x, d);
        d = fmaf(tanh_f(x1.y + q1.y), wz1.y, d);
        d = fmaf(tanh_f(x1.z + q1.z), wz1.z, d);
        d = fmaf(tanh_f(x1.w + q1.w), wz1.w, d);
        #pragma unroll
        for (int s = 32; s >= 1; s >>= 1) d += __shfl_xor(d, s);
        if (lane == 0) alog[slot] = d + baz[0];
    }
    __syncthreads();

    if (wid == 0) {
        const float v = (lane < Pn + 1) ? alog[lane] : -3.4e38f;
        float mx = v;
        #pragma unroll
        for (int s = 32; s >= 1; s >>= 1) mx = fmaxf(mx, __shfl_xor(mx, s));
        const float ev = (lane < Pn + 1) ? __expf(v - mx) : 0.f;
        float sm = ev;
        #pragma unroll
        for (int s = 32; s >= 1; s >>= 1) sm += __shfl_xor(sm, s);
        if (lane < Pn + 1) alog[lane] = ev / sm;
    }
    __syncthreads();

    const float a49 = alog[Pn];
    for (int ee = tid; ee < 512; ee += 256) {
        const float hval = b2f(Hsb[(long)r * 512 + ee]);
        float c = a49 * hval;
        const unsigned short* vp = vproj + (long)b * Pn * 512 + ee;
        #pragma unroll 7
        for (int q = 0; q < Pn; q++) c = fmaf(alog[q], b2f(vp[q * 512]), c);
        CHb[(long)r * 512 + ee] = f2b(c + hval);
    }
}

// register-resident row softmax (single global read) + length mask
__global__ __launch_bounds__(256)
void softmax_mask(float* __restrict__ out, const int* __restrict__ lengths)
{
    const int r = blockIdx.x, b = r / Tn, t = r % Tn;
    float* row = out + (long)r * Vn;
    const int tid = threadIdx.x;
    float4* row4 = (float4*)row;

    if (t >= lengths[b]) {
        f32x4* rowv = (f32x4*)row;
        const f32x4 z = {0.f, 0.f, 0.f, 0.f};
        for (int i = tid; i < Vn / 4; i += 256)
            __builtin_nontemporal_store(z, &rowv[i]);
        return;
    }

    __shared__ float red[4];
    const int lane = tid & 63, wid = tid >> 6;

    float4 rv[10];
    float mx = -3.4e38f;
    #pragma unroll
    for (int j = 0; j < 10; j++) {
        const int i = tid + j * 256;
        if (i < Vn / 4) {
            rv[j] = row4[i];
            mx = fmaxf(mx, fmaxf(fmaxf(rv[j].x, rv[j].y), fmaxf(rv[j].z, rv[j].w)));
        }
    }
    #pragma unroll
    for (int s = 32; s >= 1; s >>= 1) mx = fmaxf(mx, __shfl_xor(mx, s));
    if (lane == 0) red[wid] = mx;
    __syncthreads();
    mx = fmaxf(fmaxf(red[0], red[1]), fmaxf(red[2], red[3]));
    __syncthreads();

    float sm = 0.f;
    #pragma unroll
    for (int j = 0; j < 10; j++) {
        const int i = tid + j * 256;
        if (i < Vn / 4) {
            rv[j].x = __expf(rv[j].x - mx);
            rv[j].y = __expf(rv[j].y - mx);
            rv[j].z = __expf(rv[j].z - mx);
            rv[j].w = __expf(rv[j].w - mx);
            sm += rv[j].x + rv[j].y + rv[j].z + rv[j].w;
        }
    }
    #pragma unroll
    for (int s = 32; s >= 1; s >>= 1) sm += __shfl_xor(sm, s);
    if (lane == 0) red[wid] = sm;
    __syncthreads();
    sm = red[0] + red[1] + red[2] + red[3];
    const float inv = 1.0f / sm;

    #pragma unroll
    for (int j = 0; j < 10; j++) {
        const int i = tid + j * 256;
        if (i < Vn / 4) {
            rv[j].x *= inv; rv[j].y *= inv; rv[j].z *= inv; rv[j].w *= inv;
            row4[i] = rv[j];
        }
    }
}

extern "C" void kernel_launch(void* const* d_in, const int* in_sizes, int n_in,
                              void* d_out, int out_size, void* d_ws, size_t ws_size,
                              hipStream_t stream)
{
    (void)in_sizes; (void)n_in; (void)out_size; (void)ws_size;
    const float* v   = (const float*)d_in[0];
    const int*   w   = (const int*)  d_in[1];
    const int*   len = (const int*)  d_in[2];
    const float* emb = (const float*)d_in[3];
    const float* Wv  = (const float*)d_in[4];
    const float* bv  = (const float*)d_in[5];
    const float* Wh  = (const float*)d_in[6];
    const float* bh  = (const float*)d_in[7];
    const float* Wm  = (const float*)d_in[8];
    const float* bm  = (const float*)d_in[9];
    const float* Wl  = (const float*)d_in[10];
    const float* bl  = (const float*)d_in[11];
    const float* Wav = (const float*)d_in[12];
    const float* bav = (const float*)d_in[13];
    const float* Wah = (const float*)d_in[14];
    const float* bah = (const float*)d_in[15];
    const float* Was = (const float*)d_in[16];
    const float* bas = (const float*)d_in[17];
    const float* Waz = (const float*)d_in[18];
    const float* baz = (const float*)d_in[19];
    const float* Wp  = (const float*)d_in[20];
    const float* bp  = (const float*)d_in[21];
    float* out_f = (float*)d_out;

    // ---- workspace carve ----
    char* wsp = (char*)d_ws;
    size_t off = 0;
    auto walloc = [&](size_t bytes) -> void* {
        void* r = wsp + off;
        off += (bytes + 255) & ~(size_t)255;
        return r;
    };
    unsigned short* WpT    = (unsigned short*)walloc((size_t)Vn * 512 * 2);
    unsigned short* WvT    = (unsigned short*)walloc((size_t)512 * 1024 * 2);
    unsigned short* WlT0   = (unsigned short*)walloc((size_t)G5 * 512 * 2);
    unsigned short* WavT   = (unsigned short*)walloc((size_t)512 * 512 * 2);
    unsigned short* WahT   = (unsigned short*)walloc((size_t)512 * 512 * 2);
    unsigned short* WasT   = (unsigned short*)walloc((size_t)512 * 512 * 2);
    unsigned short* vprojb = (unsigned short*)walloc((size_t)3136 * 512 * 2);
    unsigned short* CHb    = (unsigned short*)walloc((size_t)3200 * 512 * 2);
    float* vg   = (float*)walloc((size_t)64 * 512 * 4);
    unsigned short* hB = (unsigned short*)walloc((size_t)2 * 64 * 512 * 2);  // ping-pong h (bf16)
    float* mbuf = (float*)walloc((size_t)64 * 512 * 4);
    float* vgw  = (float*)walloc((size_t)64 * G5 * 4);
    int*   ridx = (int*)walloc((size_t)3200 * 4);
    int*   dcnt = (int*)walloc(256);

    // ---- scratch in dead upper region of d_out (dead before logits GEMM) ----
    char* sp = (char*)(out_f + (size_t)3200 * G5);
    size_t off2 = 0;
    auto salloc = [&](size_t bytes) -> void* {
        void* r = sp + off2;
        off2 += (bytes + 255) & ~(size_t)255;
        return r;
    };
    unsigned short* vB  = (unsigned short*)salloc((size_t)3136 * 1024 * 2);
    unsigned short* WEb = (unsigned short*)salloc((size_t)3200 * 512 * 2);
    float* pvb = (float*)salloc((size_t)3136 * 512 * 4);
    unsigned short* Hsb = (unsigned short*)salloc((size_t)3200 * 512 * 2);
    unsigned short* Ssb = (unsigned short*)salloc((size_t)3200 * 512 * 2);
    float* PHb = (float*)salloc((size_t)3200 * 512 * 4);
    float* PSb = (float*)salloc((size_t)3200 * 512 * 4);
    unsigned short* W3T = (unsigned short*)salloc((size_t)G5 * 512 * 2);

    // ---- prep: ONE transpose launch + ONE convert/gather/compact launch ----
    mega_transpose<<<8848, 256, 0, stream>>>(Wv, WvT, Wl, WlT0, W3T,
                                             Wav, Wah, Was, WavT, WahT, WasT,
                                             Wp, WpT);
    prep_convert<<<4737, 256, 0, stream>>>(v, vB, emb, w, WEb, len, ridx, dcnt);

    // 1. vproj(bf16) = v @ Wv + bv
    gemm_mfma<0,1,0,0><<<dim3(4, 25), 256, 0, stream>>>(vB, WvT, nullptr, vprojb,
                                                        3136, 512, 1024, bv, nullptr, 1,
                                                        nullptr, nullptr, 0);
    // 2-3. fused vg + h0 (bf16 -> ping-pong slot 0) + m0
    vg_h0m0<<<64, 512, 0, stream>>>(vprojb, Wh, bh, Wm, bm, vg, hB, mbuf);
    // 4. vgw = vg @ Wl[512:1024] + bl (fp32)
    gemm64<false><<<dim3(40, 1, 1), 256, 0, stream>>>(vg, 512, Wl + (size_t)512 * G5, vgw,
                                                      64, G5, 512, bl, nullptr, 1, 0, nullptr);
    // 5. pv = vproj @ Wav + bav
    gemm_mfma<1,0,0,0><<<dim3(4, 25), 256, 0, stream>>>(vprojb, WavT, pvb, nullptr,
                                                        3136, 512, 512, bav, nullptr, 1,
                                                        nullptr, nullptr, 0);
    // 6. base = we @ Wl[0:512] + vgw[b] -> d_out rows (XCD-swizzled 1D grid)
    gemm_mfma<1,0,0,1><<<500, 256, 0, stream>>>(WEb, WlT0, out_f, nullptr,
                                                3200, G5, 512, nullptr, vgw, Tn,
                                                nullptr, nullptr, 25);
    // 7. 50-step scan: one fused launch per step (stream order = barrier)
    for (int t = 0; t < Tn; t++) {
        const size_t cur = (size_t)(t & 1) * (64 * 512);
        const size_t nxt = (size_t)((t + 1) & 1) * (64 * 512);
        scan_step<<<64, 256, 0, stream>>>(t, out_f, hB + cur, hB + nxt, mbuf, W3T,
                                          Hsb, Ssb);
    }
    // 8. PH + PS in one z=2 launch (active rows only)
    gemm_dual<<<dim3(4, 25, 2), 256, 0, stream>>>(Hsb, WahT, PHb, bah,
                                                  Ssb, WasT, PSb, bas,
                                                  512, 512, ridx, dcnt);
    // 9. attention -> CH (bf16), active rows only (XCD-local b)
    attn<<<3200, 256, 0, stream>>>(vprojb, pvb, PHb, PSb, Hsb, Waz, baz, CHb, len);
    // 10. logits = CH @ Wp + bp -> d_out (128x256 tile, 8 waves, 64x64/wave)
    gemm_8w<<<520, 512, 0, stream>>>(CHb, WpT, out_f, Vn, 512, bp, ridx, dcnt, 13);
    // 11. softmax + mask
    softmax_mask<<<3200, 256, 0, stream>>>(out_f, len);
}